// Round 3
// baseline (154.922 us; speedup 1.0000x reference)
//
#include <hip/hip_runtime.h>

#define HEADS 12
#define HIDDEN 1024
#define NOUT 1536
#define SEQ 512

typedef __bf16 bf16x8 __attribute__((ext_vector_type(8)));
typedef float f32x4 __attribute__((ext_vector_type(4)));
typedef unsigned short u16x8 __attribute__((ext_vector_type(8)));

__device__ __forceinline__ void gload_lds16(const void* g, void* l) {
  __builtin_amdgcn_global_load_lds(
      (const __attribute__((address_space(1))) unsigned int*)g,
      (__attribute__((address_space(3))) unsigned int*)l, 16, 0, 0);
}

// round-to-nearest-even fp32 -> bf16 bits (inputs are finite)
__device__ __forceinline__ unsigned short f2bf(float f) {
  union { float f; unsigned u; } x;
  x.f = f;
  unsigned r = x.u + 0x7fffu + ((x.u >> 16) & 1u);
  return (unsigned short)(r >> 16);
}

// XCD-chunked work swizzle (nwg % 8 == 0): HW block b on XCD (b&7) takes
// work item (b&7)*per + (b>>3), so consecutive work items share one XCD's L2.
__device__ __forceinline__ int swz8(int b, int per) {
  return (b & 7) * per + (b >> 3);
}

// ---------- prep: transpose W to bf16, trig table ----------
__global__ __launch_bounds__(256) void k_prep(const float* __restrict__ W,
                                              unsigned short* __restrict__ Wt,
                                              float2* __restrict__ trig) {
  __shared__ unsigned short t[32][33];
  const int bid = blockIdx.x;
  const int tid = threadIdx.x;
  if (bid < 1536) {
    int n0 = (bid % 48) * 32;
    int k0 = (bid / 48) * 32;
    int tx = tid & 31;
    int ty = tid >> 5;  // 0..7
#pragma unroll
    for (int i = 0; i < 4; ++i) {
      int k = k0 + ty + i * 8;
      t[ty + i * 8][tx] = f2bf(W[(size_t)k * NOUT + n0 + tx]);
    }
    __syncthreads();
#pragma unroll
    for (int i = 0; i < 4; ++i) {
      int n = n0 + ty + i * 8;
      Wt[(size_t)n * HIDDEN + k0 + tx] = t[tx][ty + i * 8];
    }
  } else {
    int i = (bid - 1536) * 256 + tid;  // 16384 = 512 pos x 32 freq
    int pos = i >> 5, j = i & 31;
    float inv = 1.0f / powf(10000.0f, (float)(2 * j) * (1.0f / 64.0f));
    float ang = (float)pos * inv;
    trig[i] = make_float2(cosf(ang), sinf(ang));
  }
}

// ---------- projection GEMM (fp32 A converted in-flight) + bias + RoPE ----------
__global__ __launch_bounds__(256) void k_proj(const float* __restrict__ hidden,      // 8192x1024 fp32
                                              const unsigned short* __restrict__ Bt, // 1536x1024 bf16 (W^T)
                                              const float* __restrict__ bias,        // 1536
                                              const float2* __restrict__ trig,       // 512x32
                                              unsigned short* __restrict__ qb,       // [b*12+h][512][64]
                                              unsigned short* __restrict__ kb) {
  __shared__ unsigned short As[128 * 64];
  __shared__ unsigned short Bs[128 * 64];
  const int lin = swz8(blockIdx.x, 96);  // 768 work items, 96 per XCD
  const int h = lin % 12;                // head fastest: 12 heads of one m-tile co-reside
  const int m0 = (lin / 12) * 128;
  const int n0 = h * 128;
  const int tid = threadIdx.x;
  const int wave = tid >> 6, lane = tid & 63;
  const int l15 = lane & 15, l4 = lane >> 4;
  const int wr = wave >> 1, wc = wave & 1;

  // A staging geometry: thread covers row (tid>>1), 32-col half (tid&1)
  const int ar = tid >> 1;
  const int ac = (tid & 1) * 32;
  const float* Abase = hidden + (size_t)(m0 + ar) * HIDDEN + ac;
  unsigned short* Adst = As + ar * 64 + ac;

  f32x4 acc[4][4];
#pragma unroll
  for (int a = 0; a < 4; ++a)
#pragma unroll
    for (int b2 = 0; b2 < 4; ++b2) acc[a][b2] = (f32x4){0.f, 0.f, 0.f, 0.f};

  for (int kt = 0; kt < 16; ++kt) {
    __syncthreads();
    const int kbase = kt * 64;
    // B tile: global_load_lds (bf16 Wt, 16KB)
#pragma unroll
    for (int i = 0; i < 4; ++i) {
      int chunk = i * 256 + tid;  // 0..1023
      int r = chunk >> 3, c8 = chunk & 7;
      gload_lds16(Bt + (size_t)(n0 + r) * HIDDEN + kbase + c8 * 8, Bs + chunk * 8);
    }
    // A tile: fp32 loads -> bf16 convert -> ds_write (32 elems/thread)
#pragma unroll
    for (int u = 0; u < 4; ++u) {
      float4 a0 = *(const float4*)(Abase + kbase + u * 8);
      float4 a1 = *(const float4*)(Abase + kbase + u * 8 + 4);
      u16x8 o;
      o[0] = f2bf(a0.x); o[1] = f2bf(a0.y); o[2] = f2bf(a0.z); o[3] = f2bf(a0.w);
      o[4] = f2bf(a1.x); o[5] = f2bf(a1.y); o[6] = f2bf(a1.z); o[7] = f2bf(a1.w);
      *(u16x8*)(Adst + u * 8) = o;
    }
    asm volatile("s_waitcnt vmcnt(0)" ::: "memory");
    __syncthreads();
#pragma unroll
    for (int kk = 0; kk < 2; ++kk) {
      bf16x8 af[4], bv[4];
#pragma unroll
      for (int mi = 0; mi < 4; ++mi)
        af[mi] = *(const bf16x8*)(As + (wr * 64 + mi * 16 + l15) * 64 + kk * 32 + l4 * 8);
#pragma unroll
      for (int ni = 0; ni < 4; ++ni)
        bv[ni] = *(const bf16x8*)(Bs + (wc * 64 + ni * 16 + l15) * 64 + kk * 32 + l4 * 8);
#pragma unroll
      for (int mi = 0; mi < 4; ++mi)
#pragma unroll
        for (int ni = 0; ni < 4; ++ni)
          acc[mi][ni] = __builtin_amdgcn_mfma_f32_16x16x32_bf16(af[mi], bv[ni], acc[mi][ni], 0, 0, 0);
    }
  }

  // epilogue: bias + RoPE + scale, write q/k bf16
#pragma unroll
  for (int ni = 0; ni < 4; ++ni) {
    const int c = wc * 64 + ni * 16 + l15;  // 0..127 within head: [0,64)=q, [64,128)=k
    const int qk = c >> 6;
    const int d = c & 63;
    const int j = d >> 1;
    const int odd = d & 1;
    const float bias_v = bias[n0 + c];
    unsigned short* dst = qk ? kb : qb;
    const float scale = qk ? 1.0f : 0.125f;
#pragma unroll
    for (int mi = 0; mi < 4; ++mi) {
#pragma unroll
      for (int jj = 0; jj < 4; ++jj) {
        const int row = wr * 64 + mi * 16 + l4 * 4 + jj;
        const int m = m0 + row;
        const int bb = m >> 9, pos = m & 511;
        float v = acc[mi][ni][jj] + bias_v;
        float p = __shfl_xor(v, 1);  // partner (d^1), already biased
        float2 cs = trig[pos * 32 + j];
        float o = odd ? (v * cs.x + p * cs.y) : (v * cs.x - p * cs.y);
        o *= scale;
        dst[(((size_t)bb * HEADS + h) * SEQ + pos) * 64 + d] = f2bf(o);
      }
    }
  }
}

// ---------- batched score GEMM + mask + sigmoid ----------
// One block = one (bh, q-tile); K loops over 4 tiles. Q staged once.
__global__ __launch_bounds__(256) void k_scores(const unsigned short* __restrict__ qb,
                                                const unsigned short* __restrict__ kb,
                                                const int* __restrict__ aw,
                                                float* __restrict__ out) {
  __shared__ unsigned short Qs[128 * 64];
  __shared__ unsigned short Ks[128 * 64];
  const int lin = swz8(blockIdx.x, 96);  // 768 = 192 bh x 4 q-tiles
  const int bh = lin >> 2;
  const int b = bh / HEADS;
  const int q0 = (lin & 3) * 128;
  const int tid = threadIdx.x;
  const int wave = tid >> 6, lane = tid & 63;
  const int l15 = lane & 15, l4 = lane >> 4;
  const int wr = wave >> 1, wc = wave & 1;

  const unsigned short* qsrc = qb + (size_t)bh * SEQ * 64 + (size_t)q0 * 64;
  const unsigned short* ksrc = kb + (size_t)bh * SEQ * 64;

#pragma unroll
  for (int i = 0; i < 4; ++i) {
    int chunk = i * 256 + tid;
    int r = chunk >> 3, c8 = chunk & 7;
    gload_lds16(qsrc + (size_t)r * 64 + c8 * 8, Qs + chunk * 8);
    gload_lds16(ksrc + (size_t)r * 64 + c8 * 8, Ks + chunk * 8);
  }
  asm volatile("s_waitcnt vmcnt(0)" ::: "memory");
  __syncthreads();

  for (int tk = 0; tk < 4; ++tk) {
    const int k0 = tk * 128;
    f32x4 acc[4][4];
#pragma unroll
    for (int a = 0; a < 4; ++a)
#pragma unroll
      for (int b2 = 0; b2 < 4; ++b2) acc[a][b2] = (f32x4){0.f, 0.f, 0.f, 0.f};

#pragma unroll
    for (int kk = 0; kk < 2; ++kk) {
      bf16x8 qf[4], kf[4];
#pragma unroll
      for (int mi = 0; mi < 4; ++mi)
        qf[mi] = *(const bf16x8*)(Qs + (wr * 64 + mi * 16 + l15) * 64 + kk * 32 + l4 * 8);
#pragma unroll
      for (int ni = 0; ni < 4; ++ni)
        kf[ni] = *(const bf16x8*)(Ks + (wc * 64 + ni * 16 + l15) * 64 + kk * 32 + l4 * 8);
#pragma unroll
      for (int mi = 0; mi < 4; ++mi)
#pragma unroll
        for (int ni = 0; ni < 4; ++ni)
          acc[mi][ni] = __builtin_amdgcn_mfma_f32_16x16x32_bf16(qf[mi], kf[ni], acc[mi][ni], 0, 0, 0);
    }

    // epilogue for this k-range (global stores overlap next staging latency)
#pragma unroll
    for (int ni = 0; ni < 4; ++ni) {
      const int c = wc * 64 + ni * 16 + l15;
      const int key = k0 + c;
      const int awv = aw[b * SEQ + key];
#pragma unroll
      for (int mi = 0; mi < 4; ++mi) {
#pragma unroll
        for (int jj = 0; jj < 4; ++jj) {
          const int row = wr * 64 + mi * 16 + l4 * 4 + jj;
          const int nq = q0 + row;
          float s = acc[mi][ni][jj];
          float o = (awv == 0 || nq == key) ? 0.0f : 1.0f / (1.0f + __expf(-s));
          out[((size_t)bh * SEQ + nq) * SEQ + key] = o;
        }
      }
    }

    if (tk < 3) {
      __syncthreads();  // all MFMA reads of Ks done
#pragma unroll
      for (int i = 0; i < 4; ++i) {
        int chunk = i * 256 + tid;
        int r = chunk >> 3, c8 = chunk & 7;
        gload_lds16(ksrc + (size_t)(k0 + 128 + r) * 64 + c8 * 8, Ks + chunk * 8);
      }
      asm volatile("s_waitcnt vmcnt(0)" ::: "memory");
      __syncthreads();
    }
  }
}

extern "C" void kernel_launch(void* const* d_in, const int* in_sizes, int n_in,
                              void* d_out, int out_size, void* d_ws, size_t ws_size,
                              hipStream_t stream) {
  const float* hidden = (const float*)d_in[0];
  const int* aw = (const int*)d_in[1];
  const float* W = (const float*)d_in[2];
  const float* bias = (const float*)d_in[3];
  float* out = (float*)d_out;

  char* ws = (char*)d_ws;
  unsigned short* Wt = (unsigned short*)(ws + 16777216);       //  3,145,728 B
  unsigned short* qb = (unsigned short*)(ws + 19922944);       // 12,582,912 B
  unsigned short* kb = (unsigned short*)(ws + 32505856);       // 12,582,912 B
  float2* trig = (float2*)(ws + 45088768);                     //    131,072 B

  k_prep<<<1600, 256, 0, stream>>>(W, Wt, trig);
  k_proj<<<768, 256, 0, stream>>>(hidden, Wt, bias, trig, qb, kb);
  k_scores<<<768, 256, 0, stream>>>(qb, kb, aw, out);
}

// Round 4
// 122.822 us; speedup vs baseline: 1.2614x; 1.2614x over previous
//
#include <hip/hip_runtime.h>

#define HEADS 12
#define HIDDEN 1024
#define NOUT 1536
#define SEQ 512

typedef __bf16 bf16x8 __attribute__((ext_vector_type(8)));
typedef float f32x4 __attribute__((ext_vector_type(4)));

__device__ __forceinline__ void gload_lds16(const void* g, void* l) {
  __builtin_amdgcn_global_load_lds(
      (const __attribute__((address_space(1))) unsigned int*)g,
      (__attribute__((address_space(3))) unsigned int*)l, 16, 0, 0);
}

// round-to-nearest-even fp32 -> bf16 bits (inputs are finite)
__device__ __forceinline__ unsigned short f2bf(float f) {
  union { float f; unsigned u; } x;
  x.f = f;
  unsigned r = x.u + 0x7fffu + ((x.u >> 16) & 1u);
  return (unsigned short)(r >> 16);
}

// XCD-chunked work swizzle (nwg % 8 == 0): HW block b on XCD (b&7) takes
// work item (b&7)*per + (b>>3), so consecutive work items share one XCD's L2.
__device__ __forceinline__ int swz8(int b, int per) {
  return (b & 7) * per + (b >> 3);
}

// ---------- merged prep: convert hidden, transpose W, trig table ----------
__global__ __launch_bounds__(256) void k_prep(const float* __restrict__ hidden,
                                              unsigned short* __restrict__ hidA,
                                              const float* __restrict__ W,
                                              unsigned short* __restrict__ Wt,
                                              float2* __restrict__ trig) {
  __shared__ unsigned short t[32][33];
  const int bid = blockIdx.x;
  const int tid = threadIdx.x;
  if (bid < 8192) {
    int i = bid * 256 + tid;  // 2,097,152 float4 = 16x512x1024 exact
    float4 v = ((const float4*)hidden)[i];
    ushort4 o;
    o.x = f2bf(v.x); o.y = f2bf(v.y); o.z = f2bf(v.z); o.w = f2bf(v.w);
    ((ushort4*)hidA)[i] = o;
  } else if (bid < 8192 + 1536) {
    int tt = bid - 8192;
    int n0 = (tt % 48) * 32;
    int k0 = (tt / 48) * 32;
    int tx = tid & 31;
    int ty = tid >> 5;  // 0..7
#pragma unroll
    for (int i = 0; i < 4; ++i) {
      int k = k0 + ty + i * 8;
      t[ty + i * 8][tx] = f2bf(W[(size_t)k * NOUT + n0 + tx]);
    }
    __syncthreads();
#pragma unroll
    for (int i = 0; i < 4; ++i) {
      int n = n0 + ty + i * 8;
      Wt[(size_t)n * HIDDEN + k0 + tx] = t[tx][ty + i * 8];
    }
  } else {
    int i = (bid - 9728) * 256 + tid;  // 16384 = 512 pos x 32 freq
    int pos = i >> 5, j = i & 31;
    float inv = 1.0f / powf(10000.0f, (float)(2 * j) * (1.0f / 64.0f));
    float ang = (float)pos * inv;
    trig[i] = make_float2(cosf(ang), sinf(ang));
  }
}

// ---------- projection GEMM + bias + RoPE + q-scale ----------
__global__ __launch_bounds__(256) void k_proj(const unsigned short* __restrict__ A,   // 8192x1024 bf16
                                              const unsigned short* __restrict__ Bt,  // 1536x1024 bf16 (W^T)
                                              const float* __restrict__ bias,         // 1536
                                              const float2* __restrict__ trig,        // 512x32
                                              unsigned short* __restrict__ qb,        // [b*12+h][512][64]
                                              unsigned short* __restrict__ kb) {
  __shared__ unsigned short As[128 * 64];
  __shared__ unsigned short Bs[128 * 64];
  const int lin = swz8(blockIdx.x, 96);  // 768 work items, 96 per XCD
  const int h = lin % 12;                // head fastest: 12 heads of one m-tile co-reside
  const int m0 = (lin / 12) * 128;
  const int n0 = h * 128;
  const int tid = threadIdx.x;
  const int wave = tid >> 6, lane = tid & 63;
  const int l15 = lane & 15, l4 = lane >> 4;
  const int wr = wave >> 1, wc = wave & 1;

  f32x4 acc[4][4];
#pragma unroll
  for (int a = 0; a < 4; ++a)
#pragma unroll
    for (int b2 = 0; b2 < 4; ++b2) acc[a][b2] = (f32x4){0.f, 0.f, 0.f, 0.f};

  for (int kt = 0; kt < 16; ++kt) {
    __syncthreads();
    const int kbase = kt * 64;
#pragma unroll
    for (int i = 0; i < 4; ++i) {
      int chunk = i * 256 + tid;       // 0..1023
      int r = chunk >> 3, c8 = chunk & 7;
      gload_lds16(A + (size_t)(m0 + r) * HIDDEN + kbase + c8 * 8, As + chunk * 8);
      gload_lds16(Bt + (size_t)(n0 + r) * HIDDEN + kbase + c8 * 8, Bs + chunk * 8);
    }
    asm volatile("s_waitcnt vmcnt(0)" ::: "memory");
    __syncthreads();
#pragma unroll
    for (int kk = 0; kk < 2; ++kk) {
      bf16x8 af[4], bv[4];
#pragma unroll
      for (int mi = 0; mi < 4; ++mi)
        af[mi] = *(const bf16x8*)(As + (wr * 64 + mi * 16 + l15) * 64 + kk * 32 + l4 * 8);
#pragma unroll
      for (int ni = 0; ni < 4; ++ni)
        bv[ni] = *(const bf16x8*)(Bs + (wc * 64 + ni * 16 + l15) * 64 + kk * 32 + l4 * 8);
#pragma unroll
      for (int mi = 0; mi < 4; ++mi)
#pragma unroll
        for (int ni = 0; ni < 4; ++ni)
          acc[mi][ni] = __builtin_amdgcn_mfma_f32_16x16x32_bf16(af[mi], bv[ni], acc[mi][ni], 0, 0, 0);
    }
  }

  // epilogue: bias + RoPE + scale, write q/k bf16
#pragma unroll
  for (int ni = 0; ni < 4; ++ni) {
    const int c = wc * 64 + ni * 16 + l15;  // 0..127 within head: [0,64)=q, [64,128)=k
    const int qk = c >> 6;
    const int d = c & 63;
    const int j = d >> 1;
    const int odd = d & 1;
    const float bias_v = bias[n0 + c];
    unsigned short* dst = qk ? kb : qb;
    const float scale = qk ? 1.0f : 0.125f;
#pragma unroll
    for (int mi = 0; mi < 4; ++mi) {
#pragma unroll
      for (int jj = 0; jj < 4; ++jj) {
        const int row = wr * 64 + mi * 16 + l4 * 4 + jj;
        const int m = m0 + row;
        const int bb = m >> 9, pos = m & 511;
        float v = acc[mi][ni][jj] + bias_v;
        float p = __shfl_xor(v, 1);  // partner (d^1), already biased
        float2 cs = trig[pos * 32 + j];
        float o = odd ? (v * cs.x + p * cs.y) : (v * cs.x - p * cs.y);
        o *= scale;
        dst[(((size_t)bb * HEADS + h) * SEQ + pos) * 64 + d] = f2bf(o);
      }
    }
  }
}

// ---------- batched score GEMM + mask + sigmoid ----------
// One block = one (bh, q-tile); K loops over 4 tiles, double-buffered LDS.
// Stage for tile t+1 issues BEFORE tile t's MFMA/epilogue; the compiler's
// vmcnt(0) drain at the single end-of-iter barrier covers completion.
__global__ __launch_bounds__(256) void k_scores(const unsigned short* __restrict__ qb,
                                                const unsigned short* __restrict__ kb,
                                                const int* __restrict__ aw,
                                                float* __restrict__ out) {
  __shared__ unsigned short Qs[128 * 64];
  __shared__ unsigned short Ks[2][128 * 64];
  const int lin = swz8(blockIdx.x, 96);  // 768 = 192 bh x 4 q-tiles
  const int bh = lin >> 2;
  const int b = bh / HEADS;
  const int q0 = (lin & 3) * 128;
  const int tid = threadIdx.x;
  const int wave = tid >> 6, lane = tid & 63;
  const int l15 = lane & 15, l4 = lane >> 4;
  const int wr = wave >> 1, wc = wave & 1;

  const unsigned short* qsrc = qb + (size_t)bh * SEQ * 64 + (size_t)q0 * 64;
  const unsigned short* ksrc = kb + (size_t)bh * SEQ * 64;

  // prologue: stage Q + K-tile 0
#pragma unroll
  for (int i = 0; i < 4; ++i) {
    int chunk = i * 256 + tid;  // tiles are contiguous: 128 rows x 64 cols
    gload_lds16(qsrc + chunk * 8, Qs + chunk * 8);
    gload_lds16(ksrc + chunk * 8, &Ks[0][chunk * 8]);
  }
  asm volatile("s_waitcnt vmcnt(0)" ::: "memory");
  __syncthreads();

  for (int tk = 0; tk < 4; ++tk) {
    const int cur = tk & 1;
    const int k0 = tk * 128;

    // early stage-issue for next K-tile into the other buffer (its last
    // readers finished before the previous barrier)
    if (tk < 3) {
      const unsigned short* nsrc = ksrc + (size_t)(k0 + 128) * 64;
#pragma unroll
      for (int i = 0; i < 4; ++i) {
        int chunk = i * 256 + tid;
        gload_lds16(nsrc + chunk * 8, &Ks[cur ^ 1][chunk * 8]);
      }
    }

    f32x4 acc[4][4];
#pragma unroll
    for (int a = 0; a < 4; ++a)
#pragma unroll
      for (int b2 = 0; b2 < 4; ++b2) acc[a][b2] = (f32x4){0.f, 0.f, 0.f, 0.f};

#pragma unroll
    for (int kk = 0; kk < 2; ++kk) {
      bf16x8 qf[4], kf[4];
#pragma unroll
      for (int mi = 0; mi < 4; ++mi)
        qf[mi] = *(const bf16x8*)(Qs + (wr * 64 + mi * 16 + l15) * 64 + kk * 32 + l4 * 8);
#pragma unroll
      for (int ni = 0; ni < 4; ++ni)
        kf[ni] = *(const bf16x8*)(&Ks[cur][0] + (wc * 64 + ni * 16 + l15) * 64 + kk * 32 + l4 * 8);
#pragma unroll
      for (int mi = 0; mi < 4; ++mi)
#pragma unroll
        for (int ni = 0; ni < 4; ++ni)
          acc[mi][ni] = __builtin_amdgcn_mfma_f32_16x16x32_bf16(qf[mi], kf[ni], acc[mi][ni], 0, 0, 0);
    }

    // epilogue: mask + sigmoid + store (overlaps the in-flight K stage)
#pragma unroll
    for (int ni = 0; ni < 4; ++ni) {
      const int c = wc * 64 + ni * 16 + l15;
      const int key = k0 + c;
      const int awv = aw[b * SEQ + key];
#pragma unroll
      for (int mi = 0; mi < 4; ++mi) {
#pragma unroll
        for (int jj = 0; jj < 4; ++jj) {
          const int row = wr * 64 + mi * 16 + l4 * 4 + jj;
          const int nq = q0 + row;
          float s = acc[mi][ni][jj];
          float o = (awv == 0 || nq == key) ? 0.0f : 1.0f / (1.0f + __expf(-s));
          out[((size_t)bh * SEQ + nq) * SEQ + key] = o;
        }
      }
    }

    __syncthreads();  // single per-iter barrier; drain covers stage + stores
  }
}

extern "C" void kernel_launch(void* const* d_in, const int* in_sizes, int n_in,
                              void* d_out, int out_size, void* d_ws, size_t ws_size,
                              hipStream_t stream) {
  const float* hidden = (const float*)d_in[0];
  const int* aw = (const int*)d_in[1];
  const float* W = (const float*)d_in[2];
  const float* bias = (const float*)d_in[3];
  float* out = (float*)d_out;

  char* ws = (char*)d_ws;
  unsigned short* hidA = (unsigned short*)ws;                  // 16,777,216 B
  unsigned short* Wt = (unsigned short*)(ws + 16777216);       //  3,145,728 B
  unsigned short* qb = (unsigned short*)(ws + 19922944);       // 12,582,912 B
  unsigned short* kb = (unsigned short*)(ws + 32505856);       // 12,582,912 B
  float2* trig = (float2*)(ws + 45088768);                     //    131,072 B

  k_prep<<<9792, 256, 0, stream>>>(hidden, hidA, W, Wt, trig);
  k_proj<<<768, 256, 0, stream>>>(hidA, Wt, bias, trig, qb, kb);
  k_scores<<<768, 256, 0, stream>>>(qb, kb, aw, out);
}

// Round 5
// 105.432 us; speedup vs baseline: 1.4694x; 1.1649x over previous
//
#include <hip/hip_runtime.h>

#define HEADS 12
#define HIDDEN 1024
#define NOUT 1536
#define SEQ 512

typedef __bf16 bf16x8 __attribute__((ext_vector_type(8)));
typedef float f32x4 __attribute__((ext_vector_type(4)));

__device__ __forceinline__ void gload_lds16(const void* g, void* l) {
  __builtin_amdgcn_global_load_lds(
      (const __attribute__((address_space(1))) unsigned int*)g,
      (__attribute__((address_space(3))) unsigned int*)l, 16, 0, 0);
}

// round-to-nearest-even fp32 -> bf16 bits (inputs are finite)
__device__ __forceinline__ unsigned short f2bf(float f) {
  union { float f; unsigned u; } x;
  x.f = f;
  unsigned r = x.u + 0x7fffu + ((x.u >> 16) & 1u);
  return (unsigned short)(r >> 16);
}

// XCD-chunked work swizzle (nwg % 8 == 0): HW block b on XCD (b&7) takes
// work item (b&7)*per + (b>>3), so consecutive work items share one XCD's L2.
__device__ __forceinline__ int swz8(int b, int per) {
  return (b & 7) * per + (b >> 3);
}

// ---------- merged prep: convert hidden, transpose W, trig table ----------
__global__ __launch_bounds__(256) void k_prep(const float* __restrict__ hidden,
                                              unsigned short* __restrict__ hidA,
                                              const float* __restrict__ W,
                                              unsigned short* __restrict__ Wt,
                                              float2* __restrict__ trig) {
  __shared__ unsigned short t[32][33];
  const int bid = blockIdx.x;
  const int tid = threadIdx.x;
  if (bid < 8192) {
    int i = bid * 256 + tid;  // 2,097,152 float4 = 16x512x1024 exact
    float4 v = ((const float4*)hidden)[i];
    ushort4 o;
    o.x = f2bf(v.x); o.y = f2bf(v.y); o.z = f2bf(v.z); o.w = f2bf(v.w);
    ((ushort4*)hidA)[i] = o;
  } else if (bid < 8192 + 1536) {
    int tt = bid - 8192;
    int n0 = (tt % 48) * 32;
    int k0 = (tt / 48) * 32;
    int tx = tid & 31;
    int ty = tid >> 5;  // 0..7
#pragma unroll
    for (int i = 0; i < 4; ++i) {
      int k = k0 + ty + i * 8;
      t[ty + i * 8][tx] = f2bf(W[(size_t)k * NOUT + n0 + tx]);
    }
    __syncthreads();
#pragma unroll
    for (int i = 0; i < 4; ++i) {
      int n = n0 + ty + i * 8;
      Wt[(size_t)n * HIDDEN + k0 + tx] = t[tx][ty + i * 8];
    }
  } else {
    int i = (bid - 9728) * 256 + tid;  // 16384 = 512 pos x 32 freq
    int pos = i >> 5, j = i & 31;
    float inv = 1.0f / powf(10000.0f, (float)(2 * j) * (1.0f / 64.0f));
    float ang = (float)pos * inv;
    trig[i] = make_float2(cosf(ang), sinf(ang));
  }
}

// ---------- projection GEMM + bias + RoPE + q-scale ----------
// Counted-vmcnt triple-buffered pipeline: BK=32, stage K-step t+2 while
// computing t; vmcnt(8) gates (2 stages x 4 loads in flight, never 0 in
// main loop); raw s_barrier (no forced vmcnt(0) drain); XOR-swizzled LDS
// (col-chunk ^= (row>>1)&3, involutive: pre-swizzled global source +
// swizzled ds_read); setprio around the MFMA cluster.
__global__ __launch_bounds__(256, 3) void k_proj(const unsigned short* __restrict__ A,   // 8192x1024 bf16
                                                 const unsigned short* __restrict__ Bt,  // 1536x1024 bf16 (W^T)
                                                 const float* __restrict__ bias,         // 1536
                                                 const float2* __restrict__ trig,        // 512x32
                                                 unsigned short* __restrict__ qb,        // [b*12+h][512][64]
                                                 unsigned short* __restrict__ kb) {
  __shared__ unsigned short As[3][128 * 32];
  __shared__ unsigned short Bs[3][128 * 32];
  const int lin = swz8(blockIdx.x, 96);  // 768 work items, 96 per XCD
  const int h = lin % 12;                // head fastest: 12 heads of one m-tile co-reside
  const int m0 = (lin / 12) * 128;
  const int n0 = h * 128;
  const int tid = threadIdx.x;
  const int wave = tid >> 6, lane = tid & 63;
  const int l15 = lane & 15, l4 = lane >> 4;
  const int wr = wave >> 1, wc = wave & 1;
  // swizzled col chunk for fragment reads (elements); (row>>1)&3 == (l15>>1)&3
  const int cchunk = (l4 ^ ((l15 >> 1) & 3)) * 8;

  // staging geometry: thread owns chunks c0, c1 (16B each) per operand;
  // global source col is inverse-swizzled so linear LDS + swizzled read = identity
  const int c0 = tid, c1 = 256 + tid;
  const int r0 = c0 >> 2, r1 = c1 >> 2;
  const int s0 = ((c0 & 3) ^ ((r0 >> 1) & 3)) * 8;
  const int s1 = ((c1 & 3) ^ ((r1 >> 1) & 3)) * 8;
  const unsigned short* A0 = A + (size_t)(m0 + r0) * HIDDEN + s0;
  const unsigned short* A1 = A + (size_t)(m0 + r1) * HIDDEN + s1;
  const unsigned short* B0 = Bt + (size_t)(n0 + r0) * HIDDEN + s0;
  const unsigned short* B1 = Bt + (size_t)(n0 + r1) * HIDDEN + s1;

  f32x4 acc[4][4];
#pragma unroll
  for (int a = 0; a < 4; ++a)
#pragma unroll
    for (int b2 = 0; b2 < 4; ++b2) acc[a][b2] = (f32x4){0.f, 0.f, 0.f, 0.f};

#define STAGE(KT, BUF) do {                                   \
    const int kb_ = (KT) * 32;                                \
    gload_lds16(A0 + kb_, &As[BUF][c0 * 8]);                  \
    gload_lds16(A1 + kb_, &As[BUF][c1 * 8]);                  \
    gload_lds16(B0 + kb_, &Bs[BUF][c0 * 8]);                  \
    gload_lds16(B1 + kb_, &Bs[BUF][c1 * 8]);                  \
  } while (0)

#define STEP(KT, CUR, STG, DO_STAGE, VMC) do {                                         \
    if (DO_STAGE) STAGE((KT) + 2, STG);                                                \
    asm volatile("s_waitcnt vmcnt(" #VMC ")" ::: "memory");                            \
    __builtin_amdgcn_s_barrier();                                                      \
    bf16x8 af[4], bv[4];                                                               \
    const unsigned short* Ab_ = &As[CUR][0];                                           \
    const unsigned short* Bb_ = &Bs[CUR][0];                                           \
    _Pragma("unroll") for (int mi = 0; mi < 4; ++mi)                                   \
      af[mi] = *(const bf16x8*)(Ab_ + (wr * 64 + mi * 16 + l15) * 32 + cchunk);        \
    _Pragma("unroll") for (int ni = 0; ni < 4; ++ni)                                   \
      bv[ni] = *(const bf16x8*)(Bb_ + (wc * 64 + ni * 16 + l15) * 32 + cchunk);        \
    __builtin_amdgcn_s_setprio(1);                                                     \
    _Pragma("unroll") for (int mi = 0; mi < 4; ++mi)                                   \
      _Pragma("unroll") for (int ni = 0; ni < 4; ++ni)                                 \
        acc[mi][ni] = __builtin_amdgcn_mfma_f32_16x16x32_bf16(af[mi], bv[ni],          \
                                                              acc[mi][ni], 0, 0, 0);   \
    __builtin_amdgcn_s_setprio(0);                                                     \
    asm volatile("s_waitcnt lgkmcnt(0)" ::: "memory");                                 \
    __builtin_amdgcn_s_barrier();                                                      \
  } while (0)

  // prologue: 2 K-steps in flight
  STAGE(0, 0);
  STAGE(1, 1);
  // main loop: 30 steps, buffers rotate 0,1,2; stage(t) complete is
  // guaranteed by vmcnt(8) = stages (t+1),(t+2) allowed outstanding
  for (int t = 0; t < 30; t += 3) {
    STEP(t, 0, 2, true, 8);
    STEP(t + 1, 1, 0, true, 8);
    STEP(t + 2, 2, 1, true, 8);
  }
  STEP(30, 0, 0, false, 4);
  STEP(31, 1, 0, false, 0);
#undef STEP
#undef STAGE

  // epilogue: bias + RoPE + scale, write q/k bf16
#pragma unroll
  for (int ni = 0; ni < 4; ++ni) {
    const int c = wc * 64 + ni * 16 + l15;  // 0..127 within head: [0,64)=q, [64,128)=k
    const int qk = c >> 6;
    const int d = c & 63;
    const int j = d >> 1;
    const int odd = d & 1;
    const float bias_v = bias[n0 + c];
    unsigned short* dst = qk ? kb : qb;
    const float scale = qk ? 1.0f : 0.125f;
#pragma unroll
    for (int mi = 0; mi < 4; ++mi) {
#pragma unroll
      for (int jj = 0; jj < 4; ++jj) {
        const int row = wr * 64 + mi * 16 + l4 * 4 + jj;
        const int m = m0 + row;
        const int bb = m >> 9, pos = m & 511;
        float v = acc[mi][ni][jj] + bias_v;
        float p = __shfl_xor(v, 1);  // partner (d^1), already biased
        float2 cs = trig[pos * 32 + j];
        float o = odd ? (v * cs.x + p * cs.y) : (v * cs.x - p * cs.y);
        o *= scale;
        dst[(((size_t)bb * HEADS + h) * SEQ + pos) * 64 + d] = f2bf(o);
      }
    }
  }
}

// ---------- batched score GEMM + mask + sigmoid ----------
// One block = one (bh, q-tile); K loops over 4 tiles, double-buffered LDS.
__global__ __launch_bounds__(256) void k_scores(const unsigned short* __restrict__ qb,
                                                const unsigned short* __restrict__ kb,
                                                const int* __restrict__ aw,
                                                float* __restrict__ out) {
  __shared__ unsigned short Qs[128 * 64];
  __shared__ unsigned short Ks[2][128 * 64];
  const int lin = swz8(blockIdx.x, 96);  // 768 = 192 bh x 4 q-tiles
  const int bh = lin >> 2;
  const int b = bh / HEADS;
  const int q0 = (lin & 3) * 128;
  const int tid = threadIdx.x;
  const int wave = tid >> 6, lane = tid & 63;
  const int l15 = lane & 15, l4 = lane >> 4;
  const int wr = wave >> 1, wc = wave & 1;

  const unsigned short* qsrc = qb + (size_t)bh * SEQ * 64 + (size_t)q0 * 64;
  const unsigned short* ksrc = kb + (size_t)bh * SEQ * 64;

  // prologue: stage Q + K-tile 0
#pragma unroll
  for (int i = 0; i < 4; ++i) {
    int chunk = i * 256 + tid;  // tiles are contiguous: 128 rows x 64 cols
    gload_lds16(qsrc + chunk * 8, Qs + chunk * 8);
    gload_lds16(ksrc + chunk * 8, &Ks[0][chunk * 8]);
  }
  asm volatile("s_waitcnt vmcnt(0)" ::: "memory");
  __syncthreads();

  for (int tk = 0; tk < 4; ++tk) {
    const int cur = tk & 1;
    const int k0 = tk * 128;

    // early stage-issue for next K-tile into the other buffer
    if (tk < 3) {
      const unsigned short* nsrc = ksrc + (size_t)(k0 + 128) * 64;
#pragma unroll
      for (int i = 0; i < 4; ++i) {
        int chunk = i * 256 + tid;
        gload_lds16(nsrc + chunk * 8, &Ks[cur ^ 1][chunk * 8]);
      }
    }

    f32x4 acc[4][4];
#pragma unroll
    for (int a = 0; a < 4; ++a)
#pragma unroll
      for (int b2 = 0; b2 < 4; ++b2) acc[a][b2] = (f32x4){0.f, 0.f, 0.f, 0.f};

#pragma unroll
    for (int kk = 0; kk < 2; ++kk) {
      bf16x8 qf[4], kf[4];
#pragma unroll
      for (int mi = 0; mi < 4; ++mi)
        qf[mi] = *(const bf16x8*)(Qs + (wr * 64 + mi * 16 + l15) * 64 + kk * 32 + l4 * 8);
#pragma unroll
      for (int ni = 0; ni < 4; ++ni)
        kf[ni] = *(const bf16x8*)(&Ks[cur][0] + (wc * 64 + ni * 16 + l15) * 64 + kk * 32 + l4 * 8);
#pragma unroll
      for (int mi = 0; mi < 4; ++mi)
#pragma unroll
        for (int ni = 0; ni < 4; ++ni)
          acc[mi][ni] = __builtin_amdgcn_mfma_f32_16x16x32_bf16(qf[mi], kf[ni], acc[mi][ni], 0, 0, 0);
    }

    // epilogue: mask + sigmoid + store (overlaps the in-flight K stage)
#pragma unroll
    for (int ni = 0; ni < 4; ++ni) {
      const int c = wc * 64 + ni * 16 + l15;
      const int key = k0 + c;
      const int awv = aw[b * SEQ + key];
#pragma unroll
      for (int mi = 0; mi < 4; ++mi) {
#pragma unroll
        for (int jj = 0; jj < 4; ++jj) {
          const int row = wr * 64 + mi * 16 + l4 * 4 + jj;
          const int nq = q0 + row;
          float s = acc[mi][ni][jj];
          float o = (awv == 0 || nq == key) ? 0.0f : 1.0f / (1.0f + __expf(-s));
          out[((size_t)bh * SEQ + nq) * SEQ + key] = o;
        }
      }
    }

    __syncthreads();  // single per-iter barrier; drain covers stage + stores
  }
}

extern "C" void kernel_launch(void* const* d_in, const int* in_sizes, int n_in,
                              void* d_out, int out_size, void* d_ws, size_t ws_size,
                              hipStream_t stream) {
  const float* hidden = (const float*)d_in[0];
  const int* aw = (const int*)d_in[1];
  const float* W = (const float*)d_in[2];
  const float* bias = (const float*)d_in[3];
  float* out = (float*)d_out;

  char* ws = (char*)d_ws;
  unsigned short* hidA = (unsigned short*)ws;                  // 16,777,216 B
  unsigned short* Wt = (unsigned short*)(ws + 16777216);       //  3,145,728 B
  unsigned short* qb = (unsigned short*)(ws + 19922944);       // 12,582,912 B
  unsigned short* kb = (unsigned short*)(ws + 32505856);       // 12,582,912 B
  float2* trig = (float2*)(ws + 45088768);                     //    131,072 B

  k_prep<<<9792, 256, 0, stream>>>(hidden, hidA, W, Wt, trig);
  k_proj<<<768, 256, 0, stream>>>(hidA, Wt, bias, trig, qb, kb);
  k_scores<<<768, 256, 0, stream>>>(qb, kb, aw, out);
}